// Round 1
// baseline (943.238 us; speedup 1.0000x reference)
//
#include <hip/hip_runtime.h>
#include <cstdint>
#include <cstddef>

#define EPS 1e-6f
#define KAPPA 20.0f

#define B 16
#define C 512
#define N 4096
#define J 6           // 2*K: 0..2 fg, 3..5 bg
#define XS_STRIDE 513 // 64-row x-tile, padded to kill bank conflicts

// ---------------- init: normalize mu0 over c, broadcast to all b & both models; zero acc ----------------
__global__ __launch_bounds__(512) void pmms_init(const float* __restrict__ mu_in,
                                                 float* __restrict__ mu_cur,
                                                 float* __restrict__ mu_acc) {
  int b = blockIdx.x;
  int c = threadIdx.x; // 0..511
  float v0 = mu_in[c * 3 + 0], v1 = mu_in[c * 3 + 1], v2 = mu_in[c * 3 + 2];
  float s0 = v0 * v0, s1 = v1 * v1, s2 = v2 * v2;
  for (int o = 32; o; o >>= 1) {
    s0 += __shfl_down(s0, o);
    s1 += __shfl_down(s1, o);
    s2 += __shfl_down(s2, o);
  }
  __shared__ float r[8][3];
  int w = c >> 6, ln = c & 63;
  if (ln == 0) { r[w][0] = s0; r[w][1] = s1; r[w][2] = s2; }
  __syncthreads();
  float t0 = 0.f, t1 = 0.f, t2 = 0.f;
  for (int i = 0; i < 8; ++i) { t0 += r[i][0]; t1 += r[i][1]; t2 += r[i][2]; }
  float sc0 = 1.0f / (EPS + sqrtf(t0));
  float sc1 = 1.0f / (EPS + sqrtf(t1));
  float sc2 = 1.0f / (EPS + sqrtf(t2));
  float n0 = v0 * sc0, n1 = v1 * sc1, n2 = v2 * sc2;
  size_t base = ((size_t)b * C + c) * J;
  mu_cur[base + 0] = n0; mu_cur[base + 1] = n1; mu_cur[base + 2] = n2;
  mu_cur[base + 3] = n0; mu_cur[base + 4] = n1; mu_cur[base + 5] = n2;
  #pragma unroll
  for (int j = 0; j < J; ++j) mu_acc[base + j] = 0.0f;
}

// ---------------- one EM stage, fg+bg fused, single pass over support_feature ----------------
// grid: 256 = 16 b * 16 wg; each wg loops 4 n-tiles of 64
__global__ __launch_bounds__(256, 1) void pmms_stage(const float* __restrict__ feat,
                                                     const float* __restrict__ mask,
                                                     const float* __restrict__ mu_cur,
                                                     float* __restrict__ mu_acc) {
  extern __shared__ float s[];
  float* xs  = s;                       // [64][XS_STRIDE]
  float* mus = xs + 64 * XS_STRIDE;     // [512][8]  (j 0..5 used)
  float* ms  = mus + C * 8;             // [64]
  float* zs  = ms + 64;                 // [64][8]
  float* ps  = zs + 64 * 8;             // [4][64][8] partial logits

  int b  = blockIdx.x >> 4;
  int wg = blockIdx.x & 15;
  int tid = threadIdx.x;

  // mu -> LDS (row stride 8 for aligned float4 reads)
  for (int i = tid; i < C * J; i += 256) {
    int c = i / 6, j = i - c * 6;
    mus[c * 8 + j] = mu_cur[(size_t)b * C * J + i];
  }

  float acc[12];
  #pragma unroll
  for (int j = 0; j < 12; ++j) acc[j] = 0.0f;

  const int wv = tid >> 6, ln = tid & 63;

  for (int t = 0; t < 4; ++t) {
    int n0 = (wg * 4 + t) * 64;
    __syncthreads(); // protect xs/ms/zs from previous tile's readers
    // ---- stage x tile (transposed into LDS) ----
    {
      int rpt = tid >> 4, seg = tid & 15;
      const float* fb = feat + (size_t)b * C * N + n0;
      for (int cb = 0; cb < C; cb += 16) {
        int c = cb + rpt;
        float4 v = *(const float4*)(fb + (size_t)c * N + seg * 4);
        int nl = seg * 4;
        xs[(nl + 0) * XS_STRIDE + c] = v.x;
        xs[(nl + 1) * XS_STRIDE + c] = v.y;
        xs[(nl + 2) * XS_STRIDE + c] = v.z;
        xs[(nl + 3) * XS_STRIDE + c] = v.w;
      }
      if (tid < 16) {
        float4 v = *(const float4*)(mask + (size_t)b * N + n0 + tid * 4);
        ms[tid * 4 + 0] = v.x; ms[tid * 4 + 1] = v.y;
        ms[tid * 4 + 2] = v.z; ms[tid * 4 + 3] = v.w;
      }
    }
    __syncthreads();
    // ---- phase 1: partial logits (each wave covers 128 c) ----
    {
      float m = ms[ln];
      float lf0 = 0.f, lf1 = 0.f, lf2 = 0.f, lb0 = 0.f, lb1 = 0.f, lb2 = 0.f;
      int cbeg = wv * 128;
      #pragma unroll 4
      for (int c = cbeg; c < cbeg + 128; ++c) {
        float f = xs[ln * XS_STRIDE + c];
        float xf = m * f, xb = f - xf;
        float4 m03 = *(const float4*)(mus + c * 8);
        float2 m45 = *(const float2*)(mus + c * 8 + 4);
        lf0 = fmaf(xf, m03.x, lf0); lf1 = fmaf(xf, m03.y, lf1); lf2 = fmaf(xf, m03.z, lf2);
        lb0 = fmaf(xb, m03.w, lb0); lb1 = fmaf(xb, m45.x, lb1); lb2 = fmaf(xb, m45.y, lb2);
      }
      float* pr = ps + (wv * 64 + ln) * 8;
      pr[0] = lf0; pr[1] = lf1; pr[2] = lf2; pr[3] = lb0; pr[4] = lb1; pr[5] = lb2;
    }
    __syncthreads();
    // ---- softmax (kappa=20) over k=3 per model, by first 64 threads ----
    if (tid < 64) {
      float L[6];
      #pragma unroll
      for (int j = 0; j < 6; ++j)
        L[j] = ps[(0 * 64 + tid) * 8 + j] + ps[(1 * 64 + tid) * 8 + j] +
               ps[(2 * 64 + tid) * 8 + j] + ps[(3 * 64 + tid) * 8 + j];
      float mf = fmaxf(fmaxf(L[0], L[1]), L[2]);
      float e0 = __expf(KAPPA * (L[0] - mf));
      float e1 = __expf(KAPPA * (L[1] - mf));
      float e2 = __expf(KAPPA * (L[2] - mf));
      float is = 1.0f / (e0 + e1 + e2);
      zs[tid * 8 + 0] = e0 * is; zs[tid * 8 + 1] = e1 * is; zs[tid * 8 + 2] = e2 * is;
      float mb = fmaxf(fmaxf(L[3], L[4]), L[5]);
      e0 = __expf(KAPPA * (L[3] - mb));
      e1 = __expf(KAPPA * (L[4] - mb));
      e2 = __expf(KAPPA * (L[5] - mb));
      is = 1.0f / (e0 + e1 + e2);
      zs[tid * 8 + 3] = e0 * is; zs[tid * 8 + 4] = e1 * is; zs[tid * 8 + 5] = e2 * is;
    }
    __syncthreads();
    // ---- phase 2: M-step outer-product accumulate (thread = 2 c values) ----
    {
      int c0 = tid, c1 = tid + 256;
      #pragma unroll 4
      for (int n = 0; n < 64; ++n) {
        float m2 = ms[n];
        float4 z03 = *(const float4*)(zs + n * 8);
        float2 z45 = *(const float2*)(zs + n * 8 + 4);
        float f0 = xs[n * XS_STRIDE + c0];
        float xf = m2 * f0, xb = f0 - xf;
        acc[0] = fmaf(xf, z03.x, acc[0]); acc[1] = fmaf(xf, z03.y, acc[1]); acc[2] = fmaf(xf, z03.z, acc[2]);
        acc[3] = fmaf(xb, z03.w, acc[3]); acc[4] = fmaf(xb, z45.x, acc[4]); acc[5] = fmaf(xb, z45.y, acc[5]);
        float f1 = xs[n * XS_STRIDE + c1];
        xf = m2 * f1; xb = f1 - xf;
        acc[6] = fmaf(xf, z03.x, acc[6]); acc[7]  = fmaf(xf, z03.y, acc[7]);  acc[8]  = fmaf(xf, z03.z, acc[8]);
        acc[9] = fmaf(xb, z03.w, acc[9]); acc[10] = fmaf(xb, z45.x, acc[10]); acc[11] = fmaf(xb, z45.y, acc[11]);
      }
    }
  }
  // ---- global accumulate ----
  float* dst = mu_acc + (size_t)b * C * J;
  #pragma unroll
  for (int j = 0; j < 6; ++j) atomicAdd(dst + tid * 6 + j, acc[j]);
  #pragma unroll
  for (int j = 0; j < 6; ++j) atomicAdd(dst + (size_t)(tid + 256) * 6 + j, acc[6 + j]);
}

// ---------------- L2-normalize mu over c; re-zero acc; optionally emit mu_f/mu_b outputs ----------------
// grid 96 = 16 b * 6 j; block 256 (each thread 2 c)
__global__ __launch_bounds__(256) void pmms_norm(float* __restrict__ mu_acc,
                                                 float* __restrict__ mu_cur,
                                                 float* __restrict__ out_f,
                                                 float* __restrict__ out_b,
                                                 int write_out) {
  int b = blockIdx.x / 6, j = blockIdx.x % 6;
  int tid = threadIdx.x;
  size_t base = (size_t)b * C * J + j;
  float v0 = mu_acc[base + (size_t)tid * 6];
  float v1 = mu_acc[base + (size_t)(tid + 256) * 6];
  float ss = v0 * v0 + v1 * v1;
  for (int o = 32; o; o >>= 1) ss += __shfl_down(ss, o);
  __shared__ float r[4];
  if ((tid & 63) == 0) r[tid >> 6] = ss;
  __syncthreads();
  float tot = r[0] + r[1] + r[2] + r[3];
  float sc = 1.0f / (EPS + sqrtf(tot));
  float n0 = v0 * sc, n1 = v1 * sc;
  mu_cur[base + (size_t)tid * 6] = n0;
  mu_cur[base + (size_t)(tid + 256) * 6] = n1;
  mu_acc[base + (size_t)tid * 6] = 0.0f;
  mu_acc[base + (size_t)(tid + 256) * 6] = 0.0f;
  if (write_out) {
    float* o = (j < 3) ? (out_f + (size_t)b * 1536 + j * 512)
                       : (out_b + (size_t)b * 1536 + (j - 3) * 512);
    o[tid] = n0;
    o[tid + 256] = n1;
  }
}

// ---------------- final discriminative pass on query ----------------
// grid 256 = 16 b * 16; block 256; thread = one n
__global__ __launch_bounds__(256) void pmms_query(const float* __restrict__ q,
                                                  const float* __restrict__ mu_cur,
                                                  float* __restrict__ P,
                                                  float* __restrict__ PM) {
  __shared__ float mus[C * 8];
  int b = blockIdx.x >> 4;
  int n = ((blockIdx.x & 15) << 8) + threadIdx.x;
  for (int i = threadIdx.x; i < C * J; i += 256) {
    int c = i / 6, j = i - c * 6;
    mus[c * 8 + j] = mu_cur[(size_t)b * C * J + i];
  }
  __syncthreads();
  float l0 = 0.f, l1 = 0.f, l2 = 0.f, l3 = 0.f, l4 = 0.f, l5 = 0.f;
  const float* qb = q + (size_t)b * C * N + n;
  #pragma unroll 4
  for (int c = 0; c < C; ++c) {
    float xv = qb[(size_t)c * N];
    float4 m03 = *(const float4*)(mus + c * 8);
    float2 m45 = *(const float2*)(mus + c * 8 + 4);
    l0 = fmaf(xv, m03.x, l0); l1 = fmaf(xv, m03.y, l1); l2 = fmaf(xv, m03.z, l2);
    l3 = fmaf(xv, m03.w, l3); l4 = fmaf(xv, m45.x, l4); l5 = fmaf(xv, m45.y, l5);
  }
  float mx = fmaxf(fmaxf(fmaxf(l0, l1), fmaxf(l2, l3)), fmaxf(l4, l5));
  float e0 = __expf(l0 - mx), e1 = __expf(l1 - mx), e2 = __expf(l2 - mx);
  float e3 = __expf(l3 - mx), e4 = __expf(l4 - mx), e5 = __expf(l5 - mx);
  float is = 1.0f / (e0 + e1 + e2 + e3 + e4 + e5);
  float z0 = e0 * is, z1 = e1 * is, z2 = e2 * is;
  float z3 = e3 * is, z4 = e4 * is, z5 = e5 * is;
  float* Pb = P + (size_t)b * 6 * N;
  Pb[0 * N + n] = z0; Pb[1 * N + n] = z1; Pb[2 * N + n] = z2;
  Pb[3 * N + n] = z3; Pb[4 * N + n] = z4; Pb[5 * N + n] = z5;
  float* pm = PM + (size_t)b * 2 * N;
  pm[n] = z3 + z4 + z5;      // P_b channel 0
  pm[N + n] = z0 + z1 + z2;  // P_f channel 1
}

extern "C" void kernel_launch(void* const* d_in, const int* in_sizes, int n_in,
                              void* d_out, int out_size, void* d_ws, size_t ws_size,
                              hipStream_t stream) {
  const float* feat  = (const float*)d_in[0];
  const float* mask  = (const float*)d_in[1];
  const float* query = (const float*)d_in[2];
  const float* mu_in = (const float*)d_in[3];
  float* out = (float*)d_out;

  float* mu_cur = (float*)d_ws;            // [B][C][J]
  float* mu_acc = mu_cur + (size_t)B * C * J;

  const int smem = (64 * XS_STRIDE + C * 8 + 64 + 64 * 8 + 4 * 64 * 8) * 4; // 158,208 B
  (void)hipFuncSetAttribute((const void*)pmms_stage,
                            hipFuncAttributeMaxDynamicSharedMemorySize, smem);

  pmms_init<<<B, 512, 0, stream>>>(mu_in, mu_cur, mu_acc);
  for (int st = 0; st < 10; ++st) {
    pmms_stage<<<256, 256, smem, stream>>>(feat, mask, mu_cur, mu_acc);
    pmms_norm<<<96, 256, 0, stream>>>(mu_acc, mu_cur, out, out + 24576, st == 9 ? 1 : 0);
  }
  // out layout: mu_f @0 (24576) | mu_b @24576 (24576) | Prob_map @49152 (131072) | P @180224 (393216)
  pmms_query<<<256, 256, 0, stream>>>(query, mu_cur, out + 180224, out + 49152);
}